// Round 2
// baseline (251.111 us; speedup 1.0000x reference)
//
#include <hip/hip_runtime.h>

typedef unsigned short u16;
typedef __attribute__((ext_vector_type(8))) short short8;
typedef __attribute__((ext_vector_type(4))) float f32x4;
typedef __attribute__((ext_vector_type(16))) float f32x16;

#define DEV __device__ __forceinline__

static constexpr int BATCH   = 16384;
static constexpr int NTAB    = 26;
static constexpr int VOCAB   = 100000;
static constexpr int DIM     = 64;

DEV u16 f2bf(float f){
  union { float f; unsigned u; } x; x.f = f;
  unsigned r = x.u + 0x7fffu + ((x.u >> 16) & 1u);
  return (u16)(r >> 16);
}
DEV float bf2f(u16 h){
  union { unsigned u; float f; } x; x.u = ((unsigned)h) << 16;
  return x.f;
}

// async global->LDS, 16B per lane. dst must be the wave-uniform base; HW adds lane*16.
DEV void llds16(u16* dst, const u16* src){
  __builtin_amdgcn_global_load_lds(
      (const __attribute__((address_space(1))) unsigned*)src,
      (__attribute__((address_space(3))) unsigned*)dst, 16, 0, 0);
}

// ---- weight split: src[K][N] f32 -> dst[N][3*Kpad] bf16, layout [Bh | Bl | Bh] ----
__global__ void wsplit_k(const float* __restrict__ src, u16* __restrict__ dst,
                         int K, int N, int Kpad)
{
  int i = blockIdx.x * 256 + threadIdx.x;
  if (i >= N * Kpad) return;
  int n = i / Kpad, kp = i - n * Kpad;
  float v = (kp < K) ? src[(size_t)kp * N + n] : 0.f;
  u16 hi = f2bf(v);
  u16 lo = f2bf(v - bf2f(hi));
  u16* p = dst + (size_t)n * 3 * Kpad;
  p[kp] = hi; p[Kpad + kp] = lo; p[2 * Kpad + kp] = hi;
}

// ---- dense input split: [B][13] f32 -> [B][96] bf16, layout [Ah | Ah | Al] -------
__global__ void xsplit_k(const float* __restrict__ x, u16* __restrict__ xs)
{
  int i = blockIdx.x * 256 + threadIdx.x;   // B*32 threads
  int b = i >> 5, k = i & 31;
  float v = (k < 13) ? x[b * 13 + k] : 0.f;
  u16 hi = f2bf(v);
  u16 lo = f2bf(v - bf2f(hi));
  u16* p = xs + (size_t)b * 96;
  p[k] = hi; p[32 + k] = hi; p[64 + k] = lo;
}

// ---------------- GEMM: C[M][N] = relu(A[M][K'] * Bt[N][K']^T + bias) -------------
// A, Bt bf16 row-major, split-encoded along K': A=[Ah|Ah|Al], B=[Bh|Bl|Bh] so the
// K'-dot = Ah.Bh + Ah.Bl + Al.Bh (~fp32 accuracy). 16x16x32 MFMA, 64x64 per wave.
// OUTMODE 0: write split bf16 [M][3*ldc] = [Ch|Ch|Cl]. OUTMODE 1: write fp32 [M][ldc].
template<int BM, int BN, int BK, int WM, int WN, int OUTMODE>
__global__ __launch_bounds__(WM * WN * 64)
void gemm_bt(const u16* __restrict__ A, const u16* __restrict__ Bt,
             const float* __restrict__ bias, void* __restrict__ Cout,
             int K, int nbn, int lda, int ldb, int ldc)
{
  constexpr int THREADS = WM * WN * 64;
  constexpr int ROWB    = BK * 2;        // bytes per LDS row
  constexpr int SW      = ROWB / 16 - 1; // swizzle mask over 16B slots
  constexpr int AIT     = (BM * ROWB) / (THREADS * 16);
  constexpr int BIT     = (BN * ROWB) / (THREADS * 16);

  __shared__ alignas(16) u16 Ah[BM * BK];
  __shared__ alignas(16) u16 Bh[BN * BK];

  const int tid  = threadIdx.x;
  const int lane = tid & 63;
  const int wid  = tid >> 6;
  const int wm   = wid / WN;
  const int wn   = wid % WN;
  const int m0   = (blockIdx.x / nbn) * BM;
  const int n0   = (blockIdx.x % nbn) * BN;
  const int l15  = lane & 15;
  const int lhi  = lane >> 4;

  f32x4 acc[4][4] = {};

  for (int k0 = 0; k0 < K; k0 += BK) {
    #pragma unroll
    for (int it = 0; it < AIT; ++it) {
      int loff = (it * THREADS + tid) * 16;
      int row  = loff / ROWB;
      int slot = (loff % ROWB) >> 4;
      int gs   = slot ^ (row & SW);
      llds16(Ah + (size_t)(it * THREADS + (wid << 6)) * 8,
             A + (size_t)(m0 + row) * lda + k0 + gs * 8);
    }
    #pragma unroll
    for (int it = 0; it < BIT; ++it) {
      int loff = (it * THREADS + tid) * 16;
      int row  = loff / ROWB;
      int slot = (loff % ROWB) >> 4;
      int gs   = slot ^ (row & SW);
      llds16(Bh + (size_t)(it * THREADS + (wid << 6)) * 8,
             Bt + (size_t)(n0 + row) * ldb + k0 + gs * 8);
    }
    asm volatile("s_waitcnt vmcnt(0)" ::: "memory");
    __syncthreads();

    #pragma unroll
    for (int ks = 0; ks < BK / 32; ++ks) {
      short8 af[4], bfr[4];
      #pragma unroll
      for (int mi = 0; mi < 4; ++mi) {
        int row = wm * 64 + mi * 16 + l15;
        int sl  = (ks * 4 + lhi) ^ (row & SW);
        af[mi]  = *(const short8*)(Ah + (size_t)row * BK + sl * 8);
      }
      #pragma unroll
      for (int ni = 0; ni < 4; ++ni) {
        int row = wn * 64 + ni * 16 + l15;
        int sl  = (ks * 4 + lhi) ^ (row & SW);
        bfr[ni] = *(const short8*)(Bh + (size_t)row * BK + sl * 8);
      }
      #pragma unroll
      for (int mi = 0; mi < 4; ++mi)
        #pragma unroll
        for (int ni = 0; ni < 4; ++ni)
          acc[mi][ni] = __builtin_amdgcn_mfma_f32_16x16x32_bf16(
              af[mi], bfr[ni], acc[mi][ni], 0, 0, 0);
    }
    __syncthreads();
  }

  // epilogue: bias + relu; C/D map: col = lane&15, row = (lane>>4)*4 + r  [m89]
  #pragma unroll
  for (int ni = 0; ni < 4; ++ni) {
    int col  = n0 + wn * 64 + ni * 16 + l15;
    float bv = bias[col];
    #pragma unroll
    for (int mi = 0; mi < 4; ++mi) {
      #pragma unroll
      for (int r = 0; r < 4; ++r) {
        int rowm = m0 + wm * 64 + mi * 16 + lhi * 4 + r;
        float v  = fmaxf(acc[mi][ni][r] + bv, 0.f);
        if (OUTMODE == 1) {
          ((float*)Cout)[(size_t)rowm * ldc + col] = v;
        } else {
          u16 hi = f2bf(v);
          u16 lo = f2bf(v - bf2f(hi));
          u16* p = (u16*)Cout + (size_t)rowm * 3 * ldc;
          p[col] = hi; p[ldc + col] = hi; p[2 * ldc + col] = lo;
        }
      }
    }
  }
}

// ---------------- interaction: gather + Z = T*T^T (triu), split output ------------
// One wave per batch row. T = [dx; 26 embedding rows] (27x64, rows padded to 32).
// Split Gram: Z ~ Th.Th^T + Th.Tl^T + Tl.Th^T via 3 MFMAs per k-slice.
// Output: Is[b][1344] = [Ih(448)|Ih(448)|Il(448)], I = [dx(64), triu(378), 0pad(6)]
// C/D map 32x32: col = lane&31, row = (reg&3) + 8*(reg>>2) + 4*(lane>>5)  [m74/m101]
__global__ __launch_bounds__(256)
void interact_k(const float* __restrict__ dxf, const int* __restrict__ sidx,
                const float* __restrict__ tables, u16* __restrict__ Is)
{
  const int lane = threadIdx.x & 63;
  const int b    = blockIdx.x * 4 + (threadIdx.x >> 6);
  const float* dxrow = dxf + (size_t)b * DIM;
  u16* irow = Is + (size_t)b * 1344;

  // dense part, cols [0,64)
  {
    float v  = dxrow[lane];
    u16 hi = f2bf(v);
    u16 lo = f2bf(v - bf2f(hi));
    irow[lane] = hi; irow[448 + lane] = hi; irow[896 + lane] = lo;
  }
  if (lane < 6) {
    irow[442 + lane] = 0; irow[448 + 442 + lane] = 0; irow[896 + 442 + lane] = 0;
  }

  const int r    = lane & 31;
  const int half = lane >> 5;
  const float* src = nullptr;
  if (r == 0)       src = dxrow;
  else if (r <= 26) {
    int id = sidx[b * NTAB + (r - 1)];
    src = tables + ((size_t)(r - 1) * VOCAB + (size_t)id) * DIM;
  }

  short8 fh[4], fl[4];
  #pragma unroll
  for (int ks = 0; ks < 4; ++ks) {
    short8 h = {}, l = {};
    if (src) {
      const float* p = src + ks * 16 + half * 8;
      f32x4 a = *(const f32x4*)(p);
      f32x4 c = *(const f32x4*)(p + 4);
      #pragma unroll
      for (int j = 0; j < 4; ++j) {
        u16 ha = f2bf(a[j]); h[j]     = (short)ha; l[j]     = (short)f2bf(a[j] - bf2f(ha));
        u16 hc = f2bf(c[j]); h[j + 4] = (short)hc; l[j + 4] = (short)f2bf(c[j] - bf2f(hc));
      }
    }
    fh[ks] = h; fl[ks] = l;
  }

  f32x16 z = {};
  #pragma unroll
  for (int ks = 0; ks < 4; ++ks) {
    z = __builtin_amdgcn_mfma_f32_32x32x16_bf16(fh[ks], fh[ks], z, 0, 0, 0);
    z = __builtin_amdgcn_mfma_f32_32x32x16_bf16(fh[ks], fl[ks], z, 0, 0, 0);
    z = __builtin_amdgcn_mfma_f32_32x32x16_bf16(fl[ks], fh[ks], z, 0, 0, 0);
  }

  const int col = r;
  if (col < 27) {
    #pragma unroll
    for (int reg = 0; reg < 16; ++reg) {
      int rw = (reg & 3) + 8 * (reg >> 2) + 4 * half;
      if (rw <= col) {
        int flat = rw * 27 - rw * (rw - 1) / 2 + (col - rw);
        float v  = z[reg];
        u16 hi = f2bf(v);
        u16 lo = f2bf(v - bf2f(hi));
        irow[64 + flat] = hi; irow[448 + 64 + flat] = hi; irow[896 + 64 + flat] = lo;
      }
    }
  }
}

// ---------------- final layer: out[b] = sigmoid(Y5[b,:] . w3 + b3), fp32 ----------
__global__ __launch_bounds__(256)
void final_k(const float* __restrict__ Y5, const float* __restrict__ w3,
             const float* __restrict__ b3, float* __restrict__ out)
{
  const int lane = threadIdx.x & 63;
  const int gw   = blockIdx.x * 4 + (threadIdx.x >> 6); // 1024 waves
  f32x4 wv = *(const f32x4*)(w3 + lane * 4);
  const float bb = b3[0];
  for (int i = 0; i < 16; ++i) {
    int row = gw * 16 + i;
    f32x4 xv = *(const f32x4*)(Y5 + (size_t)row * 256 + lane * 4);
    float s = xv.x * wv.x + xv.y * wv.y + xv.z * wv.z + xv.w * wv.w;
    #pragma unroll
    for (int o = 32; o; o >>= 1) s += __shfl_down(s, o);
    if (lane == 0) out[row] = 1.f / (1.f + expf(-(s + bb)));
  }
}

// ----------------------------------------------------------------------------------
extern "C" void kernel_launch(void* const* d_in, const int* in_sizes, int n_in,
                              void* d_out, int out_size, void* d_ws, size_t ws_size,
                              hipStream_t stream)
{
  const float* dense  = (const float*)d_in[0];
  const int*   sidx   = (const int*)d_in[1];
  const float* tables = (const float*)d_in[2];
  const float* bw1 = (const float*)d_in[3];  const float* bb1 = (const float*)d_in[4];
  const float* bw2 = (const float*)d_in[5];  const float* bb2 = (const float*)d_in[6];
  const float* bw3 = (const float*)d_in[7];  const float* bb3 = (const float*)d_in[8];
  const float* tw1 = (const float*)d_in[9];  const float* tb1 = (const float*)d_in[10];
  const float* tw2 = (const float*)d_in[11]; const float* tb2 = (const float*)d_in[12];
  const float* tw3 = (const float*)d_in[13]; const float* tb3 = (const float*)d_in[14];
  float* out = (float*)d_out;

  char* ws = (char*)d_ws;
  size_t off = 0;
  auto alloc = [&](size_t bytes) { size_t o = off; off += (bytes + 1023) & ~(size_t)1023; return o; };

  u16*  Xs   = (u16*)(ws + alloc((size_t)BATCH * 96 * 2));    // [B][96]  split dense
  u16*  W1s  = (u16*)(ws + alloc((size_t)512 * 96 * 2));      // [512][3*32]
  u16*  W2s  = (u16*)(ws + alloc((size_t)256 * 1536 * 2));    // [256][3*512]
  u16*  W3s  = (u16*)(ws + alloc((size_t)64 * 768 * 2));      // [64][3*256]
  u16*  WT1s = (u16*)(ws + alloc((size_t)512 * 1344 * 2));    // [512][3*448]
  u16*  WT2s = (u16*)(ws + alloc((size_t)256 * 1536 * 2));    // [256][3*512]
  u16*  A1s  = (u16*)(ws + alloc((size_t)BATCH * 1536 * 2));  // [B][3*512] (reused as B1s)
  u16*  A2s  = (u16*)(ws + alloc((size_t)BATCH * 768 * 2));   // [B][3*256]
  float* dxf = (float*)(ws + alloc((size_t)BATCH * 64 * 4));  // [B][64] fp32
  u16*  Is   = (u16*)(ws + alloc((size_t)BATCH * 1344 * 2));  // [B][3*448]
  float* Y5  = (float*)(ws + alloc((size_t)BATCH * 256 * 4)); // [B][256] fp32
  u16*  B1s  = A1s;  // A1s dead after GEMM2; reuse for top-MLP hidden
  (void)ws_size; (void)n_in; (void)in_sizes; (void)out_size;

  // input conversion + weight splits (tiny)
  xsplit_k<<<(BATCH * 32) / 256, 256, 0, stream>>>(dense, Xs);
  wsplit_k<<<(512 * 32 + 255) / 256, 256, 0, stream>>>(bw1, W1s, 13, 512, 32);
  wsplit_k<<<(256 * 512 + 255) / 256, 256, 0, stream>>>(bw2, W2s, 512, 256, 512);
  wsplit_k<<<(64 * 256 + 255) / 256, 256, 0, stream>>>(bw3, W3s, 256, 64, 256);
  wsplit_k<<<(512 * 448 + 255) / 256, 256, 0, stream>>>(tw1, WT1s, 442, 512, 448);
  wsplit_k<<<(256 * 512 + 255) / 256, 256, 0, stream>>>(tw2, WT2s, 512, 256, 512);

  // bottom MLP (split K' = 3*Kpad)
  gemm_bt<128, 128, 32, 2, 2, 0><<<(BATCH / 128) * (512 / 128), 256, 0, stream>>>(
      Xs, W1s, bb1, A1s, 96, 512 / 128, 96, 96, 512);
  gemm_bt<128, 128, 64, 2, 2, 0><<<(BATCH / 128) * (256 / 128), 256, 0, stream>>>(
      A1s, W2s, bb2, A2s, 1536, 256 / 128, 1536, 1536, 256);
  gemm_bt<128, 64, 64, 2, 1, 1><<<(BATCH / 128) * (64 / 64), 128, 0, stream>>>(
      A2s, W3s, bb3, dxf, 768, 64 / 64, 768, 768, 64);

  // gather + pairwise interaction (split output)
  interact_k<<<BATCH / 4, 256, 0, stream>>>(dxf, sidx, tables, Is);

  // top MLP
  gemm_bt<128, 128, 64, 2, 2, 0><<<(BATCH / 128) * (512 / 128), 256, 0, stream>>>(
      Is, WT1s, tb1, B1s, 1344, 512 / 128, 1344, 1344, 512);
  gemm_bt<128, 128, 64, 2, 2, 1><<<(BATCH / 128) * (256 / 128), 256, 0, stream>>>(
      B1s, WT2s, tb2, Y5, 1536, 256 / 128, 1536, 1536, 256);
  final_k<<<256, 256, 0, stream>>>(Y5, tw3, tb3, out);
}

// Round 3
// 183.329 us; speedup vs baseline: 1.3697x; 1.3697x over previous
//
#include <hip/hip_runtime.h>

typedef unsigned short u16;
typedef __attribute__((ext_vector_type(8))) short short8;
typedef __attribute__((ext_vector_type(4))) float f32x4;
typedef __attribute__((ext_vector_type(16))) float f32x16;

#define DEV __device__ __forceinline__

static constexpr int BATCH   = 16384;
static constexpr int NTAB    = 26;
static constexpr int VOCAB   = 100000;
static constexpr int DIM     = 64;

DEV u16 f2bf(float f){
  union { float f; unsigned u; } x; x.f = f;
  unsigned r = x.u + 0x7fffu + ((x.u >> 16) & 1u);
  return (u16)(r >> 16);
}
DEV float bf2f(u16 h){
  union { unsigned u; float f; } x; x.u = ((unsigned)h) << 16;
  return x.f;
}

// async global->LDS, 16B per lane. dst must be the wave-uniform base; HW adds lane*16.
DEV void llds16(u16* dst, const u16* src){
  __builtin_amdgcn_global_load_lds(
      (const __attribute__((address_space(1))) unsigned*)src,
      (__attribute__((address_space(3))) unsigned*)dst, 16, 0, 0);
}

// ---- split helpers --------------------------------------------------------------
// weight: src[K][N] f32 -> dst[N][2*Kpad] bf16 compact [Bh | Bl]
DEV void wsplit(const float* __restrict__ src, u16* __restrict__ dst,
                int K, int N, int Kpad, int i)
{
  if (i >= N * Kpad) return;
  int n = i / Kpad, kp = i - n * Kpad;
  float v = (kp < K) ? src[(size_t)kp * N + n] : 0.f;
  u16 hi = f2bf(v);
  u16 lo = f2bf(v - bf2f(hi));
  u16* p = dst + (size_t)n * 2 * Kpad;
  p[kp] = hi; p[Kpad + kp] = lo;
}

// merged prep: dense xsplit + 5 weight splits, one launch (4096 blocks x 256)
__global__ void prep_k(const float* __restrict__ dense, u16* __restrict__ Xs,
                       const float* __restrict__ bw1, u16* __restrict__ W1s,
                       const float* __restrict__ bw2, u16* __restrict__ W2s,
                       const float* __restrict__ bw3, u16* __restrict__ W3s,
                       const float* __restrict__ tw1, u16* __restrict__ WT1s,
                       const float* __restrict__ tw2, u16* __restrict__ WT2s)
{
  int blk = blockIdx.x;
  if (blk < 2048) {                       // dense: [B][13] -> [B][64] = [Ah(32)|Al(32)]
    int i = blk * 256 + threadIdx.x;      // B*32 items
    int b = i >> 5, k = i & 31;
    float v = (k < 13) ? dense[b * 13 + k] : 0.f;
    u16 hi = f2bf(v);
    u16 lo = f2bf(v - bf2f(hi));
    u16* p = Xs + (size_t)b * 64;
    p[k] = hi; p[32 + k] = lo;
  } else if (blk < 2112) {
    wsplit(bw1, W1s, 13, 512, 32, (blk - 2048) * 256 + threadIdx.x);
  } else if (blk < 2624) {
    wsplit(bw2, W2s, 512, 256, 512, (blk - 2112) * 256 + threadIdx.x);
  } else if (blk < 2688) {
    wsplit(bw3, W3s, 256, 64, 256, (blk - 2624) * 256 + threadIdx.x);
  } else if (blk < 3584) {
    wsplit(tw1, WT1s, 442, 512, 448, (blk - 2688) * 256 + threadIdx.x);
  } else {
    wsplit(tw2, WT2s, 512, 256, 512, (blk - 3584) * 256 + threadIdx.x);
  }
}

// ---------------- GEMM: C[M][N] = relu(A * B^T + bias), split-fp32 emulation ------
// A stored [M][2*Khalf] = [Ah|Al]; Bt stored [N][2*Khalf] = [Bh|Bl]. Logical
// K' = 3*Khalf walks sections (hi.hi, hi.lo, lo.hi) via staging-offset remap:
//   offA = k0<Khalf ? k0 : k0-Khalf ;  offB = k0<2*Khalf ? k0 : k0-2*Khalf
// 16x16x32 bf16 MFMA, 64x64 per wave, XOR-swizzled LDS, global_load_lds x16.
// OUTMODE 0: write compact split bf16 [M][2*ldc]=[Ch|Cl]. OUTMODE 1: fp32 [M][ldc].
template<int BM, int BN, int BK, int WM, int WN, int OUTMODE>
__global__ __launch_bounds__(WM * WN * 64)
void gemm_bt(const u16* __restrict__ A, const u16* __restrict__ Bt,
             const float* __restrict__ bias, void* __restrict__ Cout,
             int Khalf, int nbn, int lda, int ldb, int ldc)
{
  constexpr int THREADS = WM * WN * 64;
  constexpr int ROWB    = BK * 2;        // bytes per LDS row
  constexpr int SW      = ROWB / 16 - 1; // swizzle mask over 16B slots
  constexpr int AIT     = (BM * ROWB) / (THREADS * 16);
  constexpr int BIT     = (BN * ROWB) / (THREADS * 16);

  __shared__ alignas(16) u16 Ah[BM * BK];
  __shared__ alignas(16) u16 Bh[BN * BK];

  const int tid  = threadIdx.x;
  const int lane = tid & 63;
  const int wid  = tid >> 6;
  const int wm   = wid / WN;
  const int wn   = wid % WN;

  // T1: XCD-aware bijective chunk swizzle (all our grids are %8 == 0)
  int bid = blockIdx.x;
  {
    int nwg = gridDim.x;
    if ((nwg & 7) == 0) { int q = nwg >> 3; bid = (bid & 7) * q + (bid >> 3); }
  }
  const int m0   = (bid / nbn) * BM;
  const int n0   = (bid % nbn) * BN;
  const int l15  = lane & 15;
  const int lhi  = lane >> 4;

  f32x4 acc[4][4] = {};

  const int Ktot = 3 * Khalf;
  for (int k0 = 0; k0 < Ktot; k0 += BK) {
    const int kA = (k0 < Khalf)     ? k0 : k0 - Khalf;
    const int kB = (k0 < 2 * Khalf) ? k0 : k0 - 2 * Khalf;
    #pragma unroll
    for (int it = 0; it < AIT; ++it) {
      int loff = (it * THREADS + tid) * 16;
      int row  = loff / ROWB;
      int slot = (loff % ROWB) >> 4;
      int gs   = slot ^ (row & SW);
      llds16(Ah + (size_t)(it * THREADS + (wid << 6)) * 8,
             A + (size_t)(m0 + row) * lda + kA + gs * 8);
    }
    #pragma unroll
    for (int it = 0; it < BIT; ++it) {
      int loff = (it * THREADS + tid) * 16;
      int row  = loff / ROWB;
      int slot = (loff % ROWB) >> 4;
      int gs   = slot ^ (row & SW);
      llds16(Bh + (size_t)(it * THREADS + (wid << 6)) * 8,
             Bt + (size_t)(n0 + row) * ldb + kB + gs * 8);
    }
    asm volatile("s_waitcnt vmcnt(0)" ::: "memory");
    __syncthreads();

    #pragma unroll
    for (int ks = 0; ks < BK / 32; ++ks) {
      short8 af[4], bfr[4];
      #pragma unroll
      for (int mi = 0; mi < 4; ++mi) {
        int row = wm * 64 + mi * 16 + l15;
        int sl  = (ks * 4 + lhi) ^ (row & SW);
        af[mi]  = *(const short8*)(Ah + (size_t)row * BK + sl * 8);
      }
      #pragma unroll
      for (int ni = 0; ni < 4; ++ni) {
        int row = wn * 64 + ni * 16 + l15;
        int sl  = (ks * 4 + lhi) ^ (row & SW);
        bfr[ni] = *(const short8*)(Bh + (size_t)row * BK + sl * 8);
      }
      #pragma unroll
      for (int mi = 0; mi < 4; ++mi)
        #pragma unroll
        for (int ni = 0; ni < 4; ++ni)
          acc[mi][ni] = __builtin_amdgcn_mfma_f32_16x16x32_bf16(
              af[mi], bfr[ni], acc[mi][ni], 0, 0, 0);
    }
    __syncthreads();
  }

  // epilogue: bias + relu; C/D map: col = lane&15, row = (lane>>4)*4 + r  [m89]
  #pragma unroll
  for (int ni = 0; ni < 4; ++ni) {
    int col  = n0 + wn * 64 + ni * 16 + l15;
    float bv = bias[col];
    #pragma unroll
    for (int mi = 0; mi < 4; ++mi) {
      #pragma unroll
      for (int r = 0; r < 4; ++r) {
        int rowm = m0 + wm * 64 + mi * 16 + lhi * 4 + r;
        float v  = fmaxf(acc[mi][ni][r] + bv, 0.f);
        if (OUTMODE == 1) {
          ((float*)Cout)[(size_t)rowm * ldc + col] = v;
        } else {
          u16 hi = f2bf(v);
          u16 lo = f2bf(v - bf2f(hi));
          u16* p = (u16*)Cout + (size_t)rowm * 2 * ldc;
          p[col] = hi; p[ldc + col] = lo;
        }
      }
    }
  }
}

// ---------------- interaction: gather + Z = T*T^T (triu), compact split out -------
// One wave per batch row. T = [dx; 26 embedding rows] (27x64, rows padded to 32).
// Split Gram: Z ~ Th.Th^T + Th.Tl^T + Tl.Th^T via 3 MFMAs per k-slice.
// Output: Is[b][896] = [Ih(448) | Il(448)], I = [dx(64), triu(378), 0pad(6)]
// C/D map 32x32: col = lane&31, row = (reg&3) + 8*(reg>>2) + 4*(lane>>5)  [m74/m101]
__global__ __launch_bounds__(256)
void interact_k(const float* __restrict__ dxf, const int* __restrict__ sidx,
                const float* __restrict__ tables, u16* __restrict__ Is)
{
  const int lane = threadIdx.x & 63;
  const int b    = blockIdx.x * 4 + (threadIdx.x >> 6);
  const float* dxrow = dxf + (size_t)b * DIM;
  u16* irow = Is + (size_t)b * 896;

  // dense part, cols [0,64)
  {
    float v  = dxrow[lane];
    u16 hi = f2bf(v);
    u16 lo = f2bf(v - bf2f(hi));
    irow[lane] = hi; irow[448 + lane] = lo;
  }
  if (lane < 6) { irow[442 + lane] = 0; irow[448 + 442 + lane] = 0; }

  const int r    = lane & 31;
  const int half = lane >> 5;
  const float* src = nullptr;
  if (r == 0)       src = dxrow;
  else if (r <= 26) {
    int id = sidx[b * NTAB + (r - 1)];
    src = tables + ((size_t)(r - 1) * VOCAB + (size_t)id) * DIM;
  }

  short8 fh[4], fl[4];
  #pragma unroll
  for (int ks = 0; ks < 4; ++ks) {
    short8 h = {}, l = {};
    if (src) {
      const float* p = src + ks * 16 + half * 8;
      f32x4 a = *(const f32x4*)(p);
      f32x4 c = *(const f32x4*)(p + 4);
      #pragma unroll
      for (int j = 0; j < 4; ++j) {
        u16 ha = f2bf(a[j]); h[j]     = (short)ha; l[j]     = (short)f2bf(a[j] - bf2f(ha));
        u16 hc = f2bf(c[j]); h[j + 4] = (short)hc; l[j + 4] = (short)f2bf(c[j] - bf2f(hc));
      }
    }
    fh[ks] = h; fl[ks] = l;
  }

  f32x16 z = {};
  #pragma unroll
  for (int ks = 0; ks < 4; ++ks) {
    z = __builtin_amdgcn_mfma_f32_32x32x16_bf16(fh[ks], fh[ks], z, 0, 0, 0);
    z = __builtin_amdgcn_mfma_f32_32x32x16_bf16(fh[ks], fl[ks], z, 0, 0, 0);
    z = __builtin_amdgcn_mfma_f32_32x32x16_bf16(fl[ks], fh[ks], z, 0, 0, 0);
  }

  const int col = r;
  if (col < 27) {
    #pragma unroll
    for (int reg = 0; reg < 16; ++reg) {
      int rw = (reg & 3) + 8 * (reg >> 2) + 4 * half;
      if (rw <= col) {
        int flat = rw * 27 - rw * (rw - 1) / 2 + (col - rw);
        float v  = z[reg];
        u16 hi = f2bf(v);
        u16 lo = f2bf(v - bf2f(hi));
        irow[64 + flat] = hi; irow[448 + 64 + flat] = lo;
      }
    }
  }
}

// ---------------- final layer: out[b] = sigmoid(Y5[b,:] . w3 + b3), fp32 ----------
__global__ __launch_bounds__(256)
void final_k(const float* __restrict__ Y5, const float* __restrict__ w3,
             const float* __restrict__ b3, float* __restrict__ out)
{
  const int lane = threadIdx.x & 63;
  const int gw   = blockIdx.x * 4 + (threadIdx.x >> 6); // 1024 waves
  f32x4 wv = *(const f32x4*)(w3 + lane * 4);
  const float bb = b3[0];
  for (int i = 0; i < 16; ++i) {
    int row = gw * 16 + i;
    f32x4 xv = *(const f32x4*)(Y5 + (size_t)row * 256 + lane * 4);
    float s = xv.x * wv.x + xv.y * wv.y + xv.z * wv.z + xv.w * wv.w;
    #pragma unroll
    for (int o = 32; o; o >>= 1) s += __shfl_down(s, o);
    if (lane == 0) out[row] = 1.f / (1.f + expf(-(s + bb)));
  }
}

// ----------------------------------------------------------------------------------
extern "C" void kernel_launch(void* const* d_in, const int* in_sizes, int n_in,
                              void* d_out, int out_size, void* d_ws, size_t ws_size,
                              hipStream_t stream)
{
  const float* dense  = (const float*)d_in[0];
  const int*   sidx   = (const int*)d_in[1];
  const float* tables = (const float*)d_in[2];
  const float* bw1 = (const float*)d_in[3];  const float* bb1 = (const float*)d_in[4];
  const float* bw2 = (const float*)d_in[5];  const float* bb2 = (const float*)d_in[6];
  const float* bw3 = (const float*)d_in[7];  const float* bb3 = (const float*)d_in[8];
  const float* tw1 = (const float*)d_in[9];  const float* tb1 = (const float*)d_in[10];
  const float* tw2 = (const float*)d_in[11]; const float* tb2 = (const float*)d_in[12];
  const float* tw3 = (const float*)d_in[13]; const float* tb3 = (const float*)d_in[14];
  float* out = (float*)d_out;

  char* ws = (char*)d_ws;
  size_t off = 0;
  auto alloc = [&](size_t bytes) { size_t o = off; off += (bytes + 1023) & ~(size_t)1023; return o; };

  u16*  Xs   = (u16*)(ws + alloc((size_t)BATCH * 64 * 2));    // [B][2*32]
  u16*  W1s  = (u16*)(ws + alloc((size_t)512 * 64 * 2));      // [512][2*32]
  u16*  W2s  = (u16*)(ws + alloc((size_t)256 * 1024 * 2));    // [256][2*512]
  u16*  W3s  = (u16*)(ws + alloc((size_t)64 * 512 * 2));      // [64][2*256]
  u16*  WT1s = (u16*)(ws + alloc((size_t)512 * 896 * 2));     // [512][2*448]
  u16*  WT2s = (u16*)(ws + alloc((size_t)256 * 1024 * 2));    // [256][2*512]
  u16*  A1s  = (u16*)(ws + alloc((size_t)BATCH * 1024 * 2));  // [B][2*512] (reused as B1s)
  u16*  A2s  = (u16*)(ws + alloc((size_t)BATCH * 512 * 2));   // [B][2*256]
  float* dxf = (float*)(ws + alloc((size_t)BATCH * 64 * 4));  // [B][64] fp32
  u16*  Is   = (u16*)(ws + alloc((size_t)BATCH * 896 * 2));   // [B][2*448]
  float* Y5  = (float*)(ws + alloc((size_t)BATCH * 256 * 4)); // [B][256] fp32
  u16*  B1s  = A1s;  // A1s dead after bottom GEMM2; reuse for top-MLP hidden
  (void)ws_size; (void)n_in; (void)in_sizes; (void)out_size;

  // merged input conversion + weight splits (one launch)
  prep_k<<<4096, 256, 0, stream>>>(dense, Xs, bw1, W1s, bw2, W2s, bw3, W3s,
                                   tw1, WT1s, tw2, WT2s);

  // bottom MLP (logical K' = 3*Khalf via staging remap)
  gemm_bt<128, 128, 32, 2, 2, 0><<<(BATCH / 128) * (512 / 128), 256, 0, stream>>>(
      Xs, W1s, bb1, A1s, 32, 512 / 128, 64, 64, 512);
  gemm_bt<128, 128, 64, 2, 2, 0><<<(BATCH / 128) * (256 / 128), 256, 0, stream>>>(
      A1s, W2s, bb2, A2s, 512, 256 / 128, 1024, 1024, 256);
  gemm_bt<128, 64, 64, 2, 1, 1><<<(BATCH / 128) * (64 / 64), 128, 0, stream>>>(
      A2s, W3s, bb3, dxf, 256, 64 / 64, 512, 512, 64);

  // gather + pairwise interaction (compact split output)
  interact_k<<<BATCH / 4, 256, 0, stream>>>(dxf, sidx, tables, Is);

  // top MLP
  gemm_bt<128, 128, 64, 2, 2, 0><<<(BATCH / 128) * (512 / 128), 256, 0, stream>>>(
      Is, WT1s, tb1, B1s, 448, 512 / 128, 896, 896, 512);
  gemm_bt<128, 128, 64, 2, 2, 1><<<(BATCH / 128) * (256 / 128), 256, 0, stream>>>(
      B1s, WT2s, tb2, Y5, 512, 256 / 128, 1024, 1024, 256);
  final_k<<<256, 256, 0, stream>>>(Y5, tw3, tb3, out);
}

// Round 4
// 149.615 us; speedup vs baseline: 1.6784x; 1.2253x over previous
//
#include <hip/hip_runtime.h>

typedef unsigned short u16;
typedef __attribute__((ext_vector_type(8))) short short8;
typedef __attribute__((ext_vector_type(4))) float f32x4;
typedef __attribute__((ext_vector_type(16))) float f32x16;

#define DEV __device__ __forceinline__

static constexpr int BATCH   = 16384;
static constexpr int NTAB    = 26;
static constexpr int VOCAB   = 100000;
static constexpr int DIM     = 64;

DEV u16 f2bf(float f){
  union { float f; unsigned u; } x; x.f = f;
  unsigned r = x.u + 0x7fffu + ((x.u >> 16) & 1u);
  return (u16)(r >> 16);
}
DEV float bf2f(u16 h){
  union { unsigned u; float f; } x; x.u = ((unsigned)h) << 16;
  return x.f;
}

// async global->LDS, 16B per lane. dst must be the wave-uniform base; HW adds lane*16.
DEV void llds16(u16* dst, const u16* src){
  __builtin_amdgcn_global_load_lds(
      (const __attribute__((address_space(1))) unsigned*)src,
      (__attribute__((address_space(3))) unsigned*)dst, 16, 0, 0);
}

// ---- split helpers --------------------------------------------------------------
// weight: src[K][N] f32 -> dst[N][2*Kpad] bf16 compact [Bh | Bl]
DEV void wsplit(const float* __restrict__ src, u16* __restrict__ dst,
                int K, int N, int Kpad, int i)
{
  if (i >= N * Kpad) return;
  int n = i / Kpad, kp = i - n * Kpad;
  float v = (kp < K) ? src[(size_t)kp * N + n] : 0.f;
  u16 hi = f2bf(v);
  u16 lo = f2bf(v - bf2f(hi));
  u16* p = dst + (size_t)n * 2 * Kpad;
  p[kp] = hi; p[Kpad + kp] = lo;
}

// merged prep: dense xsplit + 5 weight splits, one launch (4096 blocks x 256)
__global__ void prep_k(const float* __restrict__ dense, u16* __restrict__ Xs,
                       const float* __restrict__ bw1, u16* __restrict__ W1s,
                       const float* __restrict__ bw2, u16* __restrict__ W2s,
                       const float* __restrict__ bw3, u16* __restrict__ W3s,
                       const float* __restrict__ tw1, u16* __restrict__ WT1s,
                       const float* __restrict__ tw2, u16* __restrict__ WT2s)
{
  int blk = blockIdx.x;
  if (blk < 2048) {                       // dense: [B][13] -> [B][64] = [Ah(32)|Al(32)]
    int i = blk * 256 + threadIdx.x;      // B*32 items
    int b = i >> 5, k = i & 31;
    float v = (k < 13) ? dense[b * 13 + k] : 0.f;
    u16 hi = f2bf(v);
    u16 lo = f2bf(v - bf2f(hi));
    u16* p = Xs + (size_t)b * 64;
    p[k] = hi; p[32 + k] = lo;
  } else if (blk < 2112) {
    wsplit(bw1, W1s, 13, 512, 32, (blk - 2048) * 256 + threadIdx.x);
  } else if (blk < 2624) {
    wsplit(bw2, W2s, 512, 256, 512, (blk - 2112) * 256 + threadIdx.x);
  } else if (blk < 2688) {
    wsplit(bw3, W3s, 256, 64, 256, (blk - 2624) * 256 + threadIdx.x);
  } else if (blk < 3584) {
    wsplit(tw1, WT1s, 442, 512, 448, (blk - 2688) * 256 + threadIdx.x);
  } else {
    wsplit(tw2, WT2s, 512, 256, 512, (blk - 3584) * 256 + threadIdx.x);
  }
}

// ---------------- GEMM: C[M][N] = relu(A * B^T + bias), split-fp32 emulation ------
// A stored [M][2*Khalf] = [Ah|Al]; Bt stored [N][2*Khalf] = [Bh|Bl].
// Combined K-loop: per BK-step stage FOUR tiles (A-hi, A-lo, B-hi, B-lo) into LDS
// once, then run 3 combos (hi.hi + hi.lo + lo.hi) from LDS: 2 barriers + 4 stages
// per 3x MFMA work (was 6+6). 16x16x32 bf16 MFMA, 64x64 per wave, XOR-swizzle LDS.
// OUTMODE 0: write compact split bf16 [M][2*ldc]=[Ch|Cl]. OUTMODE 1: fp32 [M][ldc].
template<int BM, int BN, int BK, int WM, int WN, int OUTMODE>
__global__ __launch_bounds__(WM * WN * 64)
void gemm_bt(const u16* __restrict__ A, const u16* __restrict__ Bt,
             const float* __restrict__ bias, void* __restrict__ Cout,
             int Khalf, int nbn, int lda, int ldb, int ldc)
{
  constexpr int THREADS = WM * WN * 64;
  constexpr int ROWB    = BK * 2;        // bytes per LDS row
  constexpr int SW      = ROWB / 16 - 1; // swizzle mask over 16B slots
  constexpr int AIT     = (BM * ROWB) / (THREADS * 16);
  constexpr int BIT     = (BN * ROWB) / (THREADS * 16);

  __shared__ alignas(16) u16 Asm[2][BM * BK];  // [hi|lo]
  __shared__ alignas(16) u16 Bsm[2][BN * BK];  // [hi|lo]

  const int tid  = threadIdx.x;
  const int lane = tid & 63;
  const int wid  = tid >> 6;
  const int wm   = wid / WN;
  const int wn   = wid % WN;

  // T1: XCD-aware bijective chunk swizzle (all our grids are %8 == 0)
  int bid = blockIdx.x;
  {
    int nwg = gridDim.x;
    if ((nwg & 7) == 0) { int q = nwg >> 3; bid = (bid & 7) * q + (bid >> 3); }
  }
  const int m0   = (bid / nbn) * BM;
  const int n0   = (bid % nbn) * BN;
  const int l15  = lane & 15;
  const int lhi  = lane >> 4;

  f32x4 acc[4][4] = {};

  for (int k0 = 0; k0 < Khalf; k0 += BK) {
    #pragma unroll
    for (int h = 0; h < 2; ++h) {
      const int koff = k0 + h * Khalf;   // hi section at k0, lo at Khalf+k0
      #pragma unroll
      for (int it = 0; it < AIT; ++it) {
        int loff = (it * THREADS + tid) * 16;
        int row  = loff / ROWB;
        int slot = (loff % ROWB) >> 4;
        int gs   = slot ^ (row & SW);
        llds16(Asm[h] + (size_t)(it * THREADS + (wid << 6)) * 8,
               A + (size_t)(m0 + row) * lda + koff + gs * 8);
      }
      #pragma unroll
      for (int it = 0; it < BIT; ++it) {
        int loff = (it * THREADS + tid) * 16;
        int row  = loff / ROWB;
        int slot = (loff % ROWB) >> 4;
        int gs   = slot ^ (row & SW);
        llds16(Bsm[h] + (size_t)(it * THREADS + (wid << 6)) * 8,
               Bt + (size_t)(n0 + row) * ldb + koff + gs * 8);
      }
    }
    asm volatile("s_waitcnt vmcnt(0)" ::: "memory");
    __syncthreads();

    #pragma unroll
    for (int ks = 0; ks < BK / 32; ++ks) {
      short8 af_h[4], af_l[4], bf_h[4], bf_l[4];
      #pragma unroll
      for (int mi = 0; mi < 4; ++mi) {
        int row = wm * 64 + mi * 16 + l15;
        int sl  = (ks * 4 + lhi) ^ (row & SW);
        af_h[mi] = *(const short8*)(Asm[0] + (size_t)row * BK + sl * 8);
        af_l[mi] = *(const short8*)(Asm[1] + (size_t)row * BK + sl * 8);
      }
      #pragma unroll
      for (int ni = 0; ni < 4; ++ni) {
        int row = wn * 64 + ni * 16 + l15;
        int sl  = (ks * 4 + lhi) ^ (row & SW);
        bf_h[ni] = *(const short8*)(Bsm[0] + (size_t)row * BK + sl * 8);
        bf_l[ni] = *(const short8*)(Bsm[1] + (size_t)row * BK + sl * 8);
      }
      #pragma unroll
      for (int mi = 0; mi < 4; ++mi)
        #pragma unroll
        for (int ni = 0; ni < 4; ++ni)
          acc[mi][ni] = __builtin_amdgcn_mfma_f32_16x16x32_bf16(
              af_h[mi], bf_h[ni], acc[mi][ni], 0, 0, 0);
      #pragma unroll
      for (int mi = 0; mi < 4; ++mi)
        #pragma unroll
        for (int ni = 0; ni < 4; ++ni)
          acc[mi][ni] = __builtin_amdgcn_mfma_f32_16x16x32_bf16(
              af_h[mi], bf_l[ni], acc[mi][ni], 0, 0, 0);
      #pragma unroll
      for (int mi = 0; mi < 4; ++mi)
        #pragma unroll
        for (int ni = 0; ni < 4; ++ni)
          acc[mi][ni] = __builtin_amdgcn_mfma_f32_16x16x32_bf16(
              af_l[mi], bf_h[ni], acc[mi][ni], 0, 0, 0);
    }
    __syncthreads();
  }

  // epilogue: bias + relu; C/D map: col = lane&15, row = (lane>>4)*4 + r  [m89]
  #pragma unroll
  for (int ni = 0; ni < 4; ++ni) {
    int col  = n0 + wn * 64 + ni * 16 + l15;
    float bv = bias[col];
    #pragma unroll
    for (int mi = 0; mi < 4; ++mi) {
      #pragma unroll
      for (int r = 0; r < 4; ++r) {
        int rowm = m0 + wm * 64 + mi * 16 + lhi * 4 + r;
        float v  = fmaxf(acc[mi][ni][r] + bv, 0.f);
        if (OUTMODE == 1) {
          ((float*)Cout)[(size_t)rowm * ldc + col] = v;
        } else {
          u16 hi = f2bf(v);
          u16 lo = f2bf(v - bf2f(hi));
          u16* p = (u16*)Cout + (size_t)rowm * 2 * ldc;
          p[col] = hi; p[ldc + col] = lo;
        }
      }
    }
  }
}

// ---------------- interaction: gather + Z = T*T^T (triu), compact split out -------
// One wave per batch row. T = [dx; 26 embedding rows] (27x64, rows padded to 32).
// Split Gram: Z ~ Th.Th^T + Th.Tl^T + Tl.Th^T via 3 MFMAs per k-slice.
// Output: Is[b][896] = [Ih(448) | Il(448)], I = [dx(64), triu(378), 0pad(6)]
// C/D map 32x32: col = lane&31, row = (reg&3) + 8*(reg>>2) + 4*(lane>>5)  [m74/m101]
__global__ __launch_bounds__(256)
void interact_k(const float* __restrict__ dxf, const int* __restrict__ sidx,
                const float* __restrict__ tables, u16* __restrict__ Is)
{
  const int lane = threadIdx.x & 63;
  const int b    = blockIdx.x * 4 + (threadIdx.x >> 6);
  const float* dxrow = dxf + (size_t)b * DIM;
  u16* irow = Is + (size_t)b * 896;

  // dense part, cols [0,64)
  {
    float v  = dxrow[lane];
    u16 hi = f2bf(v);
    u16 lo = f2bf(v - bf2f(hi));
    irow[lane] = hi; irow[448 + lane] = lo;
  }
  if (lane < 6) { irow[442 + lane] = 0; irow[448 + 442 + lane] = 0; }

  const int r    = lane & 31;
  const int half = lane >> 5;
  const float* src = nullptr;
  if (r == 0)       src = dxrow;
  else if (r <= 26) {
    int id = sidx[b * NTAB + (r - 1)];
    src = tables + ((size_t)(r - 1) * VOCAB + (size_t)id) * DIM;
  }

  short8 fh[4], fl[4];
  #pragma unroll
  for (int ks = 0; ks < 4; ++ks) {
    short8 h = {}, l = {};
    if (src) {
      const float* p = src + ks * 16 + half * 8;
      f32x4 a = *(const f32x4*)(p);
      f32x4 c = *(const f32x4*)(p + 4);
      #pragma unroll
      for (int j = 0; j < 4; ++j) {
        u16 ha = f2bf(a[j]); h[j]     = (short)ha; l[j]     = (short)f2bf(a[j] - bf2f(ha));
        u16 hc = f2bf(c[j]); h[j + 4] = (short)hc; l[j + 4] = (short)f2bf(c[j] - bf2f(hc));
      }
    }
    fh[ks] = h; fl[ks] = l;
  }

  f32x16 z = {};
  #pragma unroll
  for (int ks = 0; ks < 4; ++ks) {
    z = __builtin_amdgcn_mfma_f32_32x32x16_bf16(fh[ks], fh[ks], z, 0, 0, 0);
    z = __builtin_amdgcn_mfma_f32_32x32x16_bf16(fh[ks], fl[ks], z, 0, 0, 0);
    z = __builtin_amdgcn_mfma_f32_32x32x16_bf16(fl[ks], fh[ks], z, 0, 0, 0);
  }

  const int col = r;
  if (col < 27) {
    #pragma unroll
    for (int reg = 0; reg < 16; ++reg) {
      int rw = (reg & 3) + 8 * (reg >> 2) + 4 * half;
      if (rw <= col) {
        int flat = rw * 27 - rw * (rw - 1) / 2 + (col - rw);
        float v  = z[reg];
        u16 hi = f2bf(v);
        u16 lo = f2bf(v - bf2f(hi));
        irow[64 + flat] = hi; irow[448 + 64 + flat] = lo;
      }
    }
  }
}

// ---------------- final layer: out[b] = sigmoid(Y5[b,:] . w3 + b3), fp32 ----------
__global__ __launch_bounds__(256)
void final_k(const float* __restrict__ Y5, const float* __restrict__ w3,
             const float* __restrict__ b3, float* __restrict__ out)
{
  const int lane = threadIdx.x & 63;
  const int gw   = blockIdx.x * 4 + (threadIdx.x >> 6); // 1024 waves
  f32x4 wv = *(const f32x4*)(w3 + lane * 4);
  const float bb = b3[0];
  for (int i = 0; i < 16; ++i) {
    int row = gw * 16 + i;
    f32x4 xv = *(const f32x4*)(Y5 + (size_t)row * 256 + lane * 4);
    float s = xv.x * wv.x + xv.y * wv.y + xv.z * wv.z + xv.w * wv.w;
    #pragma unroll
    for (int o = 32; o; o >>= 1) s += __shfl_down(s, o);
    if (lane == 0) out[row] = 1.f / (1.f + expf(-(s + bb)));
  }
}

// ----------------------------------------------------------------------------------
extern "C" void kernel_launch(void* const* d_in, const int* in_sizes, int n_in,
                              void* d_out, int out_size, void* d_ws, size_t ws_size,
                              hipStream_t stream)
{
  const float* dense  = (const float*)d_in[0];
  const int*   sidx   = (const int*)d_in[1];
  const float* tables = (const float*)d_in[2];
  const float* bw1 = (const float*)d_in[3];  const float* bb1 = (const float*)d_in[4];
  const float* bw2 = (const float*)d_in[5];  const float* bb2 = (const float*)d_in[6];
  const float* bw3 = (const float*)d_in[7];  const float* bb3 = (const float*)d_in[8];
  const float* tw1 = (const float*)d_in[9];  const float* tb1 = (const float*)d_in[10];
  const float* tw2 = (const float*)d_in[11]; const float* tb2 = (const float*)d_in[12];
  const float* tw3 = (const float*)d_in[13]; const float* tb3 = (const float*)d_in[14];
  float* out = (float*)d_out;

  char* ws = (char*)d_ws;
  size_t off = 0;
  auto alloc = [&](size_t bytes) { size_t o = off; off += (bytes + 1023) & ~(size_t)1023; return o; };

  u16*  Xs   = (u16*)(ws + alloc((size_t)BATCH * 64 * 2));    // [B][2*32]
  u16*  W1s  = (u16*)(ws + alloc((size_t)512 * 64 * 2));      // [512][2*32]
  u16*  W2s  = (u16*)(ws + alloc((size_t)256 * 1024 * 2));    // [256][2*512]
  u16*  W3s  = (u16*)(ws + alloc((size_t)64 * 512 * 2));      // [64][2*256]
  u16*  WT1s = (u16*)(ws + alloc((size_t)512 * 896 * 2));     // [512][2*448]
  u16*  WT2s = (u16*)(ws + alloc((size_t)256 * 1024 * 2));    // [256][2*512]
  u16*  A1s  = (u16*)(ws + alloc((size_t)BATCH * 1024 * 2));  // [B][2*512] (reused as B1s)
  u16*  A2s  = (u16*)(ws + alloc((size_t)BATCH * 512 * 2));   // [B][2*256]
  float* dxf = (float*)(ws + alloc((size_t)BATCH * 64 * 4));  // [B][64] fp32
  u16*  Is   = (u16*)(ws + alloc((size_t)BATCH * 896 * 2));   // [B][2*448]
  float* Y5  = (float*)(ws + alloc((size_t)BATCH * 256 * 4)); // [B][256] fp32
  u16*  B1s  = A1s;  // A1s dead after bottom GEMM2; reuse for top-MLP hidden
  (void)ws_size; (void)n_in; (void)in_sizes; (void)out_size;

  // merged input conversion + weight splits (one launch)
  prep_k<<<4096, 256, 0, stream>>>(dense, Xs, bw1, W1s, bw2, W2s, bw3, W3s,
                                   tw1, WT1s, tw2, WT2s);

  // bottom MLP (combined hi/lo staging; 3 combos per staged tile-set)
  gemm_bt<128, 128, 32, 2, 2, 0><<<(BATCH / 128) * (512 / 128), 256, 0, stream>>>(
      Xs, W1s, bb1, A1s, 32, 512 / 128, 64, 64, 512);
  gemm_bt<128, 128, 64, 2, 2, 0><<<(BATCH / 128) * (256 / 128), 256, 0, stream>>>(
      A1s, W2s, bb2, A2s, 512, 256 / 128, 1024, 1024, 256);
  gemm_bt<128, 64, 64, 2, 1, 1><<<(BATCH / 128) * (64 / 64), 128, 0, stream>>>(
      A2s, W3s, bb3, dxf, 256, 64 / 64, 512, 512, 64);

  // gather + pairwise interaction (compact split output)
  interact_k<<<BATCH / 4, 256, 0, stream>>>(dxf, sidx, tables, Is);

  // top MLP
  gemm_bt<128, 128, 64, 2, 2, 0><<<(BATCH / 128) * (512 / 128), 256, 0, stream>>>(
      Is, WT1s, tb1, B1s, 448, 512 / 128, 896, 896, 512);
  gemm_bt<128, 128, 64, 2, 2, 1><<<(BATCH / 128) * (256 / 128), 256, 0, stream>>>(
      B1s, WT2s, tb2, Y5, 512, 256 / 128, 1024, 1024, 256);
  final_k<<<256, 256, 0, stream>>>(Y5, tw3, tb3, out);
}

// Round 5
// 139.409 us; speedup vs baseline: 1.8013x; 1.0732x over previous
//
#include <hip/hip_runtime.h>

typedef unsigned short u16;
typedef __attribute__((ext_vector_type(8))) short short8;
typedef __attribute__((ext_vector_type(4))) float f32x4;
typedef __attribute__((ext_vector_type(16))) float f32x16;

#define DEV __device__ __forceinline__

static constexpr int BATCH   = 16384;
static constexpr int NTAB    = 26;
static constexpr int VOCAB   = 100000;
static constexpr int DIM     = 64;

DEV u16 f2bf(float f){
  union { float f; unsigned u; } x; x.f = f;
  unsigned r = x.u + 0x7fffu + ((x.u >> 16) & 1u);
  return (u16)(r >> 16);
}
DEV float bf2f(u16 h){
  union { unsigned u; float f; } x; x.u = ((unsigned)h) << 16;
  return x.f;
}

// async global->LDS, 16B per lane. dst must be the wave-uniform base; HW adds lane*16.
DEV void llds16(u16* dst, const u16* src){
  __builtin_amdgcn_global_load_lds(
      (const __attribute__((address_space(1))) unsigned*)src,
      (__attribute__((address_space(3))) unsigned*)dst, 16, 0, 0);
}

// ---------------- prep: dense xsplit + tiled weight transpose/split ---------------
// Weight tiles: src[K][N] f32 -> dst[N][2*Kpad] bf16 compact [Bh | Bl], via 32x32
// LDS tile so global reads are coalesced f32 and writes are 64B u16 runs.
struct WDesc { const float* src; u16* dst; int K, N, Kpad; };

DEV void wtile(const float* __restrict__ src, u16* __restrict__ dst,
               int K, int N, int Kpad, int tile)
{
  __shared__ float ld[32][33];
  const int nt = N >> 5;
  const int k0 = (tile / nt) << 5;
  const int n0 = (tile % nt) << 5;
  const int tx = threadIdx.x & 31;   // fast dim
  const int ty = threadIdx.x >> 5;   // 8 rows per pass
  #pragma unroll
  for (int it = 0; it < 4; ++it) {
    int k = k0 + ty + 8 * it;
    ld[ty + 8 * it][tx] = (k < K) ? src[(size_t)k * N + n0 + tx] : 0.f;
  }
  __syncthreads();
  #pragma unroll
  for (int it = 0; it < 4; ++it) {
    int n  = n0 + ty + 8 * it;
    int kp = k0 + tx;
    float v = ld[tx][ty + 8 * it];
    u16 hi = f2bf(v);
    u16 lo = f2bf(v - bf2f(hi));
    u16* p = dst + (size_t)n * 2 * Kpad;
    p[kp] = hi; p[Kpad + kp] = lo;
  }
}

__global__ void prep_k(const float* __restrict__ dense, u16* __restrict__ Xs,
                       const float* __restrict__ bw1, u16* __restrict__ W1s,
                       const float* __restrict__ bw2, u16* __restrict__ W2s,
                       const float* __restrict__ bw3, u16* __restrict__ W3s,
                       const float* __restrict__ tw1, u16* __restrict__ WT1s,
                       const float* __restrict__ tw2, u16* __restrict__ WT2s)
{
  int blk = blockIdx.x;
  if (blk < 2048) {                       // dense: [B][13] -> [B][64] = [Ah(32)|Al(32)]
    int i = blk * 256 + threadIdx.x;      // B*32 items
    int b = i >> 5, k = i & 31;
    float v = (k < 13) ? dense[b * 13 + k] : 0.f;
    u16 hi = f2bf(v);
    u16 lo = f2bf(v - bf2f(hi));
    u16* p = Xs + (size_t)b * 64;
    p[k] = hi; p[32 + k] = lo;
  }
  else if (blk < 2064) wtile(bw1, W1s, 13, 512, 32,   blk - 2048);  // 1x16
  else if (blk < 2192) wtile(bw2, W2s, 512, 256, 512, blk - 2064);  // 16x8
  else if (blk < 2208) wtile(bw3, W3s, 256, 64, 256,  blk - 2192);  // 8x2
  else if (blk < 2432) wtile(tw1, WT1s, 442, 512, 448, blk - 2208); // 14x16
  else                 wtile(tw2, WT2s, 512, 256, 512, blk - 2432); // 16x8
}

// ---------------- GEMM: C[M][N] = relu(A * B^T + bias), split-fp32 emulation ------
// A stored [M][2*Khalf] = [Ah|Al]; Bt stored [N][2*Khalf] = [Bh|Bl].
// Per BK-step: stage 4 tiles (A-hi/lo, B-hi/lo) once, run 3 combos
// (hi.hi + hi.lo + lo.hi) from LDS. 32x32x16 bf16 MFMA (operand layout: row=lane&31,
// k-off=(lane>>5)*8, verified in interact_k), wave tile 64x64 = 2x2 frags.
// OUTMODE 0: compact split bf16 [M][2*ldc]=[Ch|Cl]. OUTMODE 1: fp32 [M][ldc].
// OUTMODE 2: fused last layer: part[(n0/BN)*BATCH + row] = sum_col relu(y)*w3[col].
template<int BM, int BN, int BK, int WM, int WN, int OUTMODE>
__global__ __launch_bounds__(WM * WN * 64)
void gemm_bt(const u16* __restrict__ A, const u16* __restrict__ Bt,
             const float* __restrict__ bias, void* __restrict__ Cout,
             int Khalf, int nbn, int lda, int ldb, int ldc,
             const float* __restrict__ w3, float* __restrict__ part)
{
  constexpr int THREADS = WM * WN * 64;
  constexpr int ROWB    = BK * 2;        // bytes per LDS row
  constexpr int SW      = ROWB / 16 - 1; // swizzle mask over 16B slots
  constexpr int AIT     = (BM * ROWB) / (THREADS * 16);
  constexpr int BIT     = (BN * ROWB) / (THREADS * 16);

  __shared__ alignas(16) u16 Asm[2][BM * BK];  // [hi|lo]
  __shared__ alignas(16) u16 Bsm[2][BN * BK];  // [hi|lo]

  const int tid  = threadIdx.x;
  const int lane = tid & 63;
  const int wid  = tid >> 6;
  const int wm   = wid / WN;
  const int wn   = wid % WN;

  // T1: XCD-aware bijective chunk swizzle (all our grids are %8 == 0)
  int bid = blockIdx.x;
  {
    int nwg = gridDim.x;
    if ((nwg & 7) == 0) { int q = nwg >> 3; bid = (bid & 7) * q + (bid >> 3); }
  }
  const int m0   = (bid / nbn) * BM;
  const int n0   = (bid % nbn) * BN;
  const int l31  = lane & 31;
  const int half = lane >> 5;

  f32x16 acc[2][2] = {};

  for (int k0 = 0; k0 < Khalf; k0 += BK) {
    #pragma unroll
    for (int h = 0; h < 2; ++h) {
      const int koff = k0 + h * Khalf;   // hi section at k0, lo at Khalf+k0
      #pragma unroll
      for (int it = 0; it < AIT; ++it) {
        int loff = (it * THREADS + tid) * 16;
        int row  = loff / ROWB;
        int slot = (loff % ROWB) >> 4;
        int gs   = slot ^ (row & SW);
        llds16(Asm[h] + (size_t)(it * THREADS + (wid << 6)) * 8,
               A + (size_t)(m0 + row) * lda + koff + gs * 8);
      }
      #pragma unroll
      for (int it = 0; it < BIT; ++it) {
        int loff = (it * THREADS + tid) * 16;
        int row  = loff / ROWB;
        int slot = (loff % ROWB) >> 4;
        int gs   = slot ^ (row & SW);
        llds16(Bsm[h] + (size_t)(it * THREADS + (wid << 6)) * 8,
               Bt + (size_t)(n0 + row) * ldb + koff + gs * 8);
      }
    }
    asm volatile("s_waitcnt vmcnt(0)" ::: "memory");
    __syncthreads();

    #pragma unroll
    for (int ks = 0; ks < BK / 16; ++ks) {
      short8 ah[2], al[2], bh[2], bl[2];
      #pragma unroll
      for (int mi = 0; mi < 2; ++mi) {
        int row = wm * 64 + mi * 32 + l31;
        int sl  = (2 * ks + half) ^ (row & SW);
        ah[mi] = *(const short8*)(Asm[0] + (size_t)row * BK + sl * 8);
        al[mi] = *(const short8*)(Asm[1] + (size_t)row * BK + sl * 8);
      }
      #pragma unroll
      for (int ni = 0; ni < 2; ++ni) {
        int row = wn * 64 + ni * 32 + l31;
        int sl  = (2 * ks + half) ^ (row & SW);
        bh[ni] = *(const short8*)(Bsm[0] + (size_t)row * BK + sl * 8);
        bl[ni] = *(const short8*)(Bsm[1] + (size_t)row * BK + sl * 8);
      }
      #pragma unroll
      for (int mi = 0; mi < 2; ++mi)
        #pragma unroll
        for (int ni = 0; ni < 2; ++ni)
          acc[mi][ni] = __builtin_amdgcn_mfma_f32_32x32x16_bf16(
              ah[mi], bh[ni], acc[mi][ni], 0, 0, 0);
      #pragma unroll
      for (int mi = 0; mi < 2; ++mi)
        #pragma unroll
        for (int ni = 0; ni < 2; ++ni)
          acc[mi][ni] = __builtin_amdgcn_mfma_f32_32x32x16_bf16(
              ah[mi], bl[ni], acc[mi][ni], 0, 0, 0);
      #pragma unroll
      for (int mi = 0; mi < 2; ++mi)
        #pragma unroll
        for (int ni = 0; ni < 2; ++ni)
          acc[mi][ni] = __builtin_amdgcn_mfma_f32_32x32x16_bf16(
              al[mi], bh[ni], acc[mi][ni], 0, 0, 0);
    }
    __syncthreads();
  }

  // epilogue. 32x32 C/D map: col = lane&31, row = (reg&3)+8*(reg>>2)+4*(lane>>5) [m74/m101]
  if constexpr (OUTMODE == 2) {
    // fused final layer: per-row partial dot of relu(y + bias) with w3
    __shared__ float redbuf[WN][BM];
    #pragma unroll
    for (int mi = 0; mi < 2; ++mi) {
      #pragma unroll
      for (int reg = 0; reg < 16; ++reg) {
        float s = 0.f;
        #pragma unroll
        for (int ni = 0; ni < 2; ++ni) {
          int col = n0 + wn * 64 + ni * 32 + l31;
          s += fmaxf(acc[mi][ni][reg] + bias[col], 0.f) * w3[col];
        }
        #pragma unroll
        for (int off = 16; off; off >>= 1) s += __shfl_xor(s, off);
        if (l31 == 0)
          redbuf[wn][wm * 64 + mi * 32 + (reg & 3) + 8 * (reg >> 2) + 4 * half] = s;
      }
    }
    __syncthreads();
    if (tid < BM) {
      float s = redbuf[0][tid];
      #pragma unroll
      for (int w = 1; w < WN; ++w) s += redbuf[w][tid];
      part[(size_t)(n0 / BN) * BATCH + m0 + tid] = s;
    }
  } else {
    #pragma unroll
    for (int ni = 0; ni < 2; ++ni) {
      int col  = n0 + wn * 64 + ni * 32 + l31;
      float bv = bias[col];
      #pragma unroll
      for (int mi = 0; mi < 2; ++mi) {
        #pragma unroll
        for (int reg = 0; reg < 16; ++reg) {
          int rowm = m0 + wm * 64 + mi * 32 + (reg & 3) + 8 * (reg >> 2) + 4 * half;
          float v  = fmaxf(acc[mi][ni][reg] + bv, 0.f);
          if (OUTMODE == 1) {
            ((float*)Cout)[(size_t)rowm * ldc + col] = v;
          } else {
            u16 hi = f2bf(v);
            u16 lo = f2bf(v - bf2f(hi));
            u16* p = (u16*)Cout + (size_t)rowm * 2 * ldc;
            p[col] = hi; p[ldc + col] = lo;
          }
        }
      }
    }
  }
}

// ---------------- interaction: gather + Z = T*T^T (triu), compact split out -------
// One wave per batch row. T = [dx; 26 embedding rows] (27x64, rows padded to 32).
// Split Gram: Z ~ Th.Th^T + Th.Tl^T + Tl.Th^T via 3 MFMAs per k-slice.
// Output: Is[b][896] = [Ih(448) | Il(448)], I = [dx(64), triu(378), 0pad(6)]
__global__ __launch_bounds__(256)
void interact_k(const float* __restrict__ dxf, const int* __restrict__ sidx,
                const float* __restrict__ tables, u16* __restrict__ Is)
{
  const int lane = threadIdx.x & 63;
  const int b    = blockIdx.x * 4 + (threadIdx.x >> 6);
  const float* dxrow = dxf + (size_t)b * DIM;
  u16* irow = Is + (size_t)b * 896;

  // dense part, cols [0,64)
  {
    float v  = dxrow[lane];
    u16 hi = f2bf(v);
    u16 lo = f2bf(v - bf2f(hi));
    irow[lane] = hi; irow[448 + lane] = lo;
  }
  if (lane < 6) { irow[442 + lane] = 0; irow[448 + 442 + lane] = 0; }

  const int r    = lane & 31;
  const int half = lane >> 5;
  const float* src = nullptr;
  if (r == 0)       src = dxrow;
  else if (r <= 26) {
    int id = sidx[b * NTAB + (r - 1)];
    src = tables + ((size_t)(r - 1) * VOCAB + (size_t)id) * DIM;
  }

  short8 fh[4], fl[4];
  #pragma unroll
  for (int ks = 0; ks < 4; ++ks) {
    short8 h = {}, l = {};
    if (src) {
      const float* p = src + ks * 16 + half * 8;
      f32x4 a = *(const f32x4*)(p);
      f32x4 c = *(const f32x4*)(p + 4);
      #pragma unroll
      for (int j = 0; j < 4; ++j) {
        u16 ha = f2bf(a[j]); h[j]     = (short)ha; l[j]     = (short)f2bf(a[j] - bf2f(ha));
        u16 hc = f2bf(c[j]); h[j + 4] = (short)hc; l[j + 4] = (short)f2bf(c[j] - bf2f(hc));
      }
    }
    fh[ks] = h; fl[ks] = l;
  }

  f32x16 z = {};
  #pragma unroll
  for (int ks = 0; ks < 4; ++ks) {
    z = __builtin_amdgcn_mfma_f32_32x32x16_bf16(fh[ks], fh[ks], z, 0, 0, 0);
    z = __builtin_amdgcn_mfma_f32_32x32x16_bf16(fh[ks], fl[ks], z, 0, 0, 0);
    z = __builtin_amdgcn_mfma_f32_32x32x16_bf16(fl[ks], fh[ks], z, 0, 0, 0);
  }

  const int col = r;
  if (col < 27) {
    #pragma unroll
    for (int reg = 0; reg < 16; ++reg) {
      int rw = (reg & 3) + 8 * (reg >> 2) + 4 * half;
      if (rw <= col) {
        int flat = rw * 27 - rw * (rw - 1) / 2 + (col - rw);
        float v  = z[reg];
        u16 hi = f2bf(v);
        u16 lo = f2bf(v - bf2f(hi));
        irow[64 + flat] = hi; irow[448 + 64 + flat] = lo;
      }
    }
  }
}

// ---------------- finisher: out[b] = sigmoid(part0[b] + part1[b] + b3) ------------
__global__ __launch_bounds__(256)
void final2_k(const float* __restrict__ part, const float* __restrict__ b3,
              float* __restrict__ out)
{
  int i = blockIdx.x * 256 + threadIdx.x;
  float s = part[i] + part[BATCH + i] + b3[0];
  out[i] = 1.f / (1.f + expf(-s));
}

// ----------------------------------------------------------------------------------
extern "C" void kernel_launch(void* const* d_in, const int* in_sizes, int n_in,
                              void* d_out, int out_size, void* d_ws, size_t ws_size,
                              hipStream_t stream)
{
  const float* dense  = (const float*)d_in[0];
  const int*   sidx   = (const int*)d_in[1];
  const float* tables = (const float*)d_in[2];
  const float* bw1 = (const float*)d_in[3];  const float* bb1 = (const float*)d_in[4];
  const float* bw2 = (const float*)d_in[5];  const float* bb2 = (const float*)d_in[6];
  const float* bw3 = (const float*)d_in[7];  const float* bb3 = (const float*)d_in[8];
  const float* tw1 = (const float*)d_in[9];  const float* tb1 = (const float*)d_in[10];
  const float* tw2 = (const float*)d_in[11]; const float* tb2 = (const float*)d_in[12];
  const float* tw3 = (const float*)d_in[13]; const float* tb3 = (const float*)d_in[14];
  float* out = (float*)d_out;

  char* ws = (char*)d_ws;
  size_t off = 0;
  auto alloc = [&](size_t bytes) { size_t o = off; off += (bytes + 1023) & ~(size_t)1023; return o; };

  u16*  Xs   = (u16*)(ws + alloc((size_t)BATCH * 64 * 2));    // [B][2*32]
  u16*  W1s  = (u16*)(ws + alloc((size_t)512 * 64 * 2));      // [512][2*32]
  u16*  W2s  = (u16*)(ws + alloc((size_t)256 * 1024 * 2));    // [256][2*512]
  u16*  W3s  = (u16*)(ws + alloc((size_t)64 * 512 * 2));      // [64][2*256]
  u16*  WT1s = (u16*)(ws + alloc((size_t)512 * 896 * 2));     // [512][2*448]
  u16*  WT2s = (u16*)(ws + alloc((size_t)256 * 1024 * 2));    // [256][2*512]
  u16*  A1s  = (u16*)(ws + alloc((size_t)BATCH * 1024 * 2));  // [B][2*512] (reused as B1s)
  u16*  A2s  = (u16*)(ws + alloc((size_t)BATCH * 512 * 2));   // [B][2*256]
  float* dxf = (float*)(ws + alloc((size_t)BATCH * 64 * 4));  // [B][64] fp32
  u16*  Is   = (u16*)(ws + alloc((size_t)BATCH * 896 * 2));   // [B][2*448]
  float* part= (float*)(ws + alloc((size_t)2 * BATCH * 4));   // [2][B] fused-dot partials
  u16*  B1s  = A1s;  // A1s dead after bottom GEMM2; reuse for top-MLP hidden
  (void)ws_size; (void)n_in; (void)in_sizes; (void)out_size;

  // merged input conversion + tiled weight transpose/split (one launch)
  prep_k<<<2560, 256, 0, stream>>>(dense, Xs, bw1, W1s, bw2, W2s, bw3, W3s,
                                   tw1, WT1s, tw2, WT2s);

  // bottom MLP (combined hi/lo staging; 3 combos per staged tile-set)
  gemm_bt<128, 128, 32, 2, 2, 0><<<(BATCH / 128) * (512 / 128), 256, 0, stream>>>(
      Xs, W1s, bb1, A1s, 32, 512 / 128, 64, 64, 512, nullptr, nullptr);
  gemm_bt<128, 128, 64, 2, 2, 0><<<(BATCH / 128) * (256 / 128), 256, 0, stream>>>(
      A1s, W2s, bb2, A2s, 512, 256 / 128, 1024, 1024, 256, nullptr, nullptr);
  gemm_bt<128, 64, 64, 2, 1, 1><<<(BATCH / 128) * (64 / 64), 128, 0, stream>>>(
      A2s, W3s, bb3, dxf, 256, 64 / 64, 512, 512, 64, nullptr, nullptr);

  // gather + pairwise interaction (compact split output)
  interact_k<<<BATCH / 4, 256, 0, stream>>>(dxf, sidx, tables, Is);

  // top MLP (layer 3 fused into layer-2 epilogue as partial dots)
  gemm_bt<128, 128, 64, 2, 2, 0><<<(BATCH / 128) * (512 / 128), 256, 0, stream>>>(
      Is, WT1s, tb1, B1s, 448, 512 / 128, 896, 896, 512, nullptr, nullptr);
  gemm_bt<128, 128, 64, 2, 2, 2><<<(BATCH / 128) * (256 / 128), 256, 0, stream>>>(
      B1s, WT2s, tb2, nullptr, 512, 256 / 128, 1024, 1024, 256, tw3, part);
  final2_k<<<BATCH / 256, 256, 0, stream>>>(part, tb3, out);
}